// Round 1
// baseline (747.589 us; speedup 1.0000x reference)
//
#include <hip/hip_runtime.h>

#define Bb 32
#define Tt 64
#define Nn 300
#define Dd 128
#define NC (Nn * Dd)              // 38400 columns per (b,t) row
#define BTND ((size_t)Tt * NC)    // 2457600 elems per batch

// Kernel 1: fused Q[b,t,n] = sum_d src*wt1  and  K[b,t,d] = sum_n wt3*src.
// One block per (b,t); 4 waves; lane covers 2 consecutive d via float2.
__global__ __launch_bounds__(256) void qk_kernel(
        const float* __restrict__ src, const float* __restrict__ wt1,
        const float* __restrict__ wt3, float* __restrict__ Q,
        float* __restrict__ K) {
    __shared__ float wt3_s[Nn];
    __shared__ float kred[4 * Dd];
    const int tid = threadIdx.x;
    const int wave = tid >> 6, lane = tid & 63;
    for (int i = tid; i < Nn; i += 256) wt3_s[i] = wt3[i];
    __syncthreads();
    const int d0 = lane * 2;
    const float2 w1 = *(const float2*)(wt1 + d0);
    const float* sbt = src + (size_t)blockIdx.x * NC;
    float* Qrow = Q + (size_t)blockIdx.x * Nn;
    float kx = 0.f, ky = 0.f;
    for (int n = wave; n < Nn; n += 4) {
        float2 v = *(const float2*)(sbt + n * Dd + d0);
        float q = v.x * w1.x + v.y * w1.y;
        #pragma unroll
        for (int off = 32; off > 0; off >>= 1) q += __shfl_down(q, off, 64);
        if (lane == 0) Qrow[n] = q;
        float w3 = wt3_s[n];
        kx = fmaf(w3, v.x, kx);
        ky = fmaf(w3, v.y, ky);
    }
    kred[wave * Dd + d0] = kx;
    kred[wave * Dd + d0 + 1] = ky;
    __syncthreads();
    if (tid < Dd) {
        float s = kred[tid] + kred[Dd + tid] + kred[2 * Dd + tid] + kred[3 * Dd + tid];
        K[(size_t)blockIdx.x * Dd + tid] = s;
    }
}

// Kernel 2: scores[b,q,k] = sum_d (sum_n Q[b,q,n]*wt2[n,d]) * K[b,k,d].
// One block per (b,q); 128 threads (thread = d for QW phase, = k for score phase).
__global__ __launch_bounds__(128) void score_kernel(
        const float* __restrict__ Q, const float* __restrict__ K,
        const float* __restrict__ wt2, float* __restrict__ scores) {
    __shared__ float qs[Nn];
    __shared__ float qws[Dd];
    const int tid = threadIdx.x;
    const int bq = blockIdx.x;  // b*T + q
    const float* Qrow = Q + (size_t)bq * Nn;
    for (int i = tid; i < Nn; i += 128) qs[i] = Qrow[i];
    __syncthreads();
    float qw = 0.f;
    for (int n = 0; n < Nn; ++n) qw = fmaf(qs[n], wt2[n * Dd + tid], qw);
    qws[tid] = qw;
    __syncthreads();
    if (tid < Tt) {
        const int b = bq >> 6;  // T = 64
        const float* Krow = K + (size_t)(b * Tt + tid) * Dd;
        float s = 0.f;
        for (int d = 0; d < Dd; ++d) s = fmaf(qws[d], Krow[d], s);
        scores[(size_t)bq * Tt + tid] = s;
    }
}

// Kernel 3: softmax over the BATCH axis (axis 0), per (q,k) pair.
__global__ __launch_bounds__(256) void softmax_b_kernel(
        const float* __restrict__ scores, float* __restrict__ att) {
    const int idx = blockIdx.x * 256 + threadIdx.x;  // qk index in [0, T*T)
    float v[Bb];
    float m = -1e30f;
    #pragma unroll
    for (int b = 0; b < Bb; ++b) {
        v[b] = scores[b * (Tt * Tt) + idx];
        m = fmaxf(m, v[b]);
    }
    float sum = 0.f;
    #pragma unroll
    for (int b = 0; b < Bb; ++b) {
        float e = __expf(v[b] - m);
        v[b] = e;
        sum += e;
    }
    const float inv = 1.0f / sum;
    #pragma unroll
    for (int b = 0; b < Bb; ++b) att[b * (Tt * Tt) + idx] = v[b] * inv;
}

// Kernel 4: out[b,a,j] = sum_t (att[b,t,a] + (t==a)) * src[b,t,j].
// Residual folded into att via +identity. blockIdx.y = b, blockIdx.x = column
// chunk of 256; each thread owns one column j and all 64 'a' accumulators.
__global__ __launch_bounds__(256, 4) void mix_kernel(
        const float* __restrict__ src, const float* __restrict__ att,
        float* __restrict__ out) {
    __shared__ float att_s[Tt * Tt];  // [t][a], 16 KB
    const int tid = threadIdx.x;
    const int b = blockIdx.y;
    for (int i = tid; i < Tt * Tt; i += 256) {
        int t = i >> 6, a = i & 63;
        float v = att[(size_t)b * Tt * Tt + i];
        att_s[i] = v + (t == a ? 1.0f : 0.0f);
    }
    __syncthreads();
    const int j = blockIdx.x * 256 + tid;
    const float* sb = src + (size_t)b * BTND + j;
    float* ob = out + (size_t)b * BTND + j;
    float acc[Tt];
    #pragma unroll
    for (int a = 0; a < Tt; ++a) acc[a] = 0.f;
    float x = sb[0];
    for (int t = 0; t < Tt; ++t) {
        float xn = 0.f;
        if (t < Tt - 1) xn = sb[(size_t)(t + 1) * NC];  // prefetch next row
        const float* arow = att_s + t * Tt;
        #pragma unroll
        for (int a = 0; a < Tt; ++a) acc[a] = fmaf(arow[a], x, acc[a]);
        x = xn;
    }
    #pragma unroll
    for (int a = 0; a < Tt; ++a) ob[(size_t)a * NC] = acc[a];
}

extern "C" void kernel_launch(void* const* d_in, const int* in_sizes, int n_in,
                              void* d_out, int out_size, void* d_ws, size_t ws_size,
                              hipStream_t stream) {
    const float* src = (const float*)d_in[0];
    const float* wt1 = (const float*)d_in[1];
    const float* wt2 = (const float*)d_in[2];
    const float* wt3 = (const float*)d_in[3];
    float* out = (float*)d_out;

    float* ws = (float*)d_ws;
    float* Q      = ws;                               // B*T*N  = 614400 floats
    float* K      = Q + (size_t)Bb * Tt * Nn;         // B*T*D  = 262144 floats
    float* scores = K + (size_t)Bb * Tt * Dd;         // B*T*T  = 131072 floats
    float* att    = scores + (size_t)Bb * Tt * Tt;    // B*T*T  = 131072 floats
    // total ws use: ~4.6 MB

    qk_kernel<<<Bb * Tt, 256, 0, stream>>>(src, wt1, wt3, Q, K);
    score_kernel<<<Bb * Tt, 128, 0, stream>>>(Q, K, wt2, scores);
    softmax_b_kernel<<<(Tt * Tt) / 256, 256, 0, stream>>>(scores, att);
    dim3 g4(NC / 256, Bb);
    mix_kernel<<<g4, 256, 0, stream>>>(src, att, out);
}